// Round 4
// baseline (403.050 us; speedup 1.0000x reference)
//
#include <hip/hip_runtime.h>
#include <cstdint>
#include <cstddef>

// ---------------------------------------------------------------------------
// out = cos(x @ Wp^T + phi) @ Wc^T
//   x: [32768,1024] fp32, Wp/Wc: [1024,1024] fp32, phi flat [1024] fp32.
// R4: R2's fused x-cast GEMM1 revisited WITH the R3 XCD swizzle (R2's 171 us
// was traffic: 543 MB fetch from 8-XCD duplication of fp32 A; swizzle fixes
// that). Kills the 41 us cast_all dispatch. GEMM2 unchanged from R3.
// GEMM core: m97 structure, 128x128 tile, BK=32, 16x16x32 bf16 MFMA.
// Fixed ~155 us of dur_us is harness restore/poison — not controllable.
// ---------------------------------------------------------------------------

typedef __attribute__((ext_vector_type(8))) short short8;
typedef __attribute__((ext_vector_type(4))) float f32x4;

__device__ __forceinline__ unsigned short f2bf(float f) {
  unsigned u = __float_as_uint(f);
  u += 0x7FFFu + ((u >> 16) & 1u);   // RNE
  return (unsigned short)(u >> 16);
}

// pack two fp32 -> bf16x2 (round-half-up)
__device__ __forceinline__ unsigned pack2bf(float lo, float hi) {
  return ((__float_as_uint(lo) + 0x8000u) >> 16) |
         ((__float_as_uint(hi) + 0x8000u) & 0xFFFF0000u);
}

__device__ __forceinline__ void async_load16(const void* g, const void* l) {
  __builtin_amdgcn_global_load_lds(
      (const __attribute__((address_space(1))) void*)g,
      (__attribute__((address_space(3))) void*)l,
      16, 0, 0);
}

// --------------------- Wp + Wc fp32 -> bf16 (one tiny launch) ---------------
__global__ __launch_bounds__(256) void cast_w(
    const float* __restrict__ Wp, const float* __restrict__ Wc,
    unsigned short* __restrict__ dp, unsigned short* __restrict__ dc) {
  int i = (blockIdx.x * 256 + threadIdx.x) * 4;   // < 2097152
  const float* s;
  unsigned short* d;
  int j;
  if (i < 1048576) { s = Wp; d = dp; j = i; }
  else             { s = Wc; d = dc; j = i - 1048576; }
  const float4 v = *(const float4*)(s + j);
  ushort4 o;
  o.x = f2bf(v.x); o.y = f2bf(v.y); o.z = f2bf(v.z); o.w = f2bf(v.w);
  *(ushort4*)(d + j) = o;
}

constexpr int TM = 128, TN = 128, BK = 32;
constexpr int Kdim = 1024, Ndim = 1024;

// ------------- GEMM1: Q = cos(x @ Wp^T + phi) -> bf16, x fp32 in ------------
// A staged fp32 global -> regs -> bf16 ds_write_b128; one-iter reg prefetch.
__global__ __launch_bounds__(256, 2) void gemm1_fused(
    const float* __restrict__ X,            // [32768,1024] fp32
    const unsigned short* __restrict__ B,   // Wp bf16 [1024,1024]
    const float* __restrict__ phi,          // [1024]
    unsigned short* __restrict__ Q) {       // [32768,1024] bf16
  __shared__ unsigned short As[TM * BK];    // 8 KB
  __shared__ unsigned short Bs[TN * BK];    // 8 KB

  const int tid  = threadIdx.x;
  const int lane = tid & 63;
  const int wv   = tid >> 6;
  // XCD swizzle: 8 n-siblings of an m-block share blockIdx % 8 -> same XCD L2
  const int m_blk = blockIdx.x & 255;
  const int n_blk = blockIdx.x >> 8;
  const long row0 = (long)m_blk * TM;
  const int  col0 = n_blk * TN;

  // A staging: thread t -> row tid>>1, k-half tid&1 (16 fp32 = 64B)
  const int rowA  = tid >> 1;
  const int halfA = tid & 1;
  const float* gA = X + (row0 + rowA) * Kdim + halfA * 16;
  uint4* wA = (uint4*)((unsigned short*)As + rowA * BK + halfA * 16);  // 32B-aligned

  // B staging DMA: wave-uniform base + lane*16
  const int s_row  = lane >> 2;
  const int s_colb = (lane & 3) * 16;

  const int lane15 = lane & 15;
  const int quad   = lane >> 4;
  const int wm = (wv >> 1) * 64;
  const int wn = (wv & 1) * 64;

  f32x4 acc[4][4];
#pragma unroll
  for (int mi = 0; mi < 4; ++mi)
#pragma unroll
    for (int ni = 0; ni < 4; ++ni) {
      f32x4 z = {0.f, 0.f, 0.f, 0.f};
      acc[mi][ni] = z;
    }

  // register prefetch of first A k-tile
  float4 a0, a1, a2, a3;
  {
    const float4* p = (const float4*)(gA);
    a0 = p[0]; a1 = p[1]; a2 = p[2]; a3 = p[3];
  }

  for (int k0 = 0; k0 < Kdim; k0 += BK) {
    // cvt + LDS write of current A tile (2x ds_write_b128)
    uint4 w0, w1;
    w0.x = pack2bf(a0.x, a0.y); w0.y = pack2bf(a0.z, a0.w);
    w0.z = pack2bf(a1.x, a1.y); w0.w = pack2bf(a1.z, a1.w);
    w1.x = pack2bf(a2.x, a2.y); w1.y = pack2bf(a2.z, a2.w);
    w1.z = pack2bf(a3.x, a3.y); w1.w = pack2bf(a3.z, a3.w);
    wA[0] = w0; wA[1] = w1;
    // B tile DMA
#pragma unroll
    for (int j = 0; j < 2; ++j) {
      const int chunk = wv * 2 + j;
      const int row = chunk * 16 + s_row;
      const char* gb = (const char*)(B + (long)(col0 + row) * Kdim + k0) + s_colb;
      async_load16(gb, (const char*)Bs + chunk * 1024);
    }
    __syncthreads();

    // prefetch next A k-tile during MFMA phase (wraps harmlessly at end)
    {
      const int kn = (k0 + BK) & (Kdim - 1);
      const float4* p = (const float4*)(gA + kn);
      a0 = p[0]; a1 = p[1]; a2 = p[2]; a3 = p[3];
    }

    short8 af[4], bfr[4];
#pragma unroll
    for (int mi = 0; mi < 4; ++mi)
      af[mi] = *(const short8*)(As + (wm + mi * 16 + lane15) * BK + quad * 8);
#pragma unroll
    for (int ni = 0; ni < 4; ++ni)
      bfr[ni] = *(const short8*)(Bs + (wn + ni * 16 + lane15) * BK + quad * 8);
#pragma unroll
    for (int mi = 0; mi < 4; ++mi)
#pragma unroll
      for (int ni = 0; ni < 4; ++ni)
        acc[mi][ni] = __builtin_amdgcn_mfma_f32_16x16x32_bf16(
            af[mi], bfr[ni], acc[mi][ni], 0, 0, 0);
    __syncthreads();
  }

  // epilogue: cos(acc + phi[col]) -> bf16.  C/D: col=lane&15, row=quad*4+reg
  float ph[4];
#pragma unroll
  for (int ni = 0; ni < 4; ++ni)
    ph[ni] = phi[col0 + wn + ni * 16 + lane15];
#pragma unroll
  for (int mi = 0; mi < 4; ++mi) {
    const long rbase = row0 + wm + mi * 16 + quad * 4;
#pragma unroll
    for (int ni = 0; ni < 4; ++ni) {
      const int c = col0 + wn + ni * 16 + lane15;
#pragma unroll
      for (int r = 0; r < 4; ++r) {
        float v = __cosf(acc[mi][ni][r] + ph[ni]);
        Q[(rbase + r) * Ndim + c] = f2bf(v);
      }
    }
  }
}

// ---------------- GEMM2: out = Q @ Wc^T, bf16 in, fp32 out ------------------
__global__ __launch_bounds__(256, 2) void gemm2_bt(
    const unsigned short* __restrict__ A,   // Q bf16 [32768,1024]
    const unsigned short* __restrict__ B,   // Wc bf16 [1024,1024]
    float* __restrict__ C) {                // [32768,1024] fp32
  __shared__ unsigned short As[TM * BK];
  __shared__ unsigned short Bs[TN * BK];

  const int tid  = threadIdx.x;
  const int lane = tid & 63;
  const int wv   = tid >> 6;
  const int m_blk = blockIdx.x & 255;
  const int n_blk = blockIdx.x >> 8;
  const long row0 = (long)m_blk * TM;
  const int  col0 = n_blk * TN;

  const int s_row  = lane >> 2;
  const int s_colb = (lane & 3) * 16;

  const int lane15 = lane & 15;
  const int quad   = lane >> 4;
  const int wm = (wv >> 1) * 64;
  const int wn = (wv & 1) * 64;

  f32x4 acc[4][4];
#pragma unroll
  for (int mi = 0; mi < 4; ++mi)
#pragma unroll
    for (int ni = 0; ni < 4; ++ni) {
      f32x4 z = {0.f, 0.f, 0.f, 0.f};
      acc[mi][ni] = z;
    }

  for (int k0 = 0; k0 < Kdim; k0 += BK) {
#pragma unroll
    for (int j = 0; j < 2; ++j) {
      const int chunk = wv * 2 + j;
      const int row = chunk * 16 + s_row;
      const char* ga = (const char*)(A + (row0 + row) * Kdim + k0) + s_colb;
      async_load16(ga, (const char*)As + chunk * 1024);
      const char* gb = (const char*)(B + (long)(col0 + row) * Kdim + k0) + s_colb;
      async_load16(gb, (const char*)Bs + chunk * 1024);
    }
    __syncthreads();

    short8 af[4], bfr[4];
#pragma unroll
    for (int mi = 0; mi < 4; ++mi)
      af[mi] = *(const short8*)(As + (wm + mi * 16 + lane15) * BK + quad * 8);
#pragma unroll
    for (int ni = 0; ni < 4; ++ni)
      bfr[ni] = *(const short8*)(Bs + (wn + ni * 16 + lane15) * BK + quad * 8);
#pragma unroll
    for (int mi = 0; mi < 4; ++mi)
#pragma unroll
      for (int ni = 0; ni < 4; ++ni)
        acc[mi][ni] = __builtin_amdgcn_mfma_f32_16x16x32_bf16(
            af[mi], bfr[ni], acc[mi][ni], 0, 0, 0);
    __syncthreads();
  }

#pragma unroll
  for (int mi = 0; mi < 4; ++mi) {
    const long rbase = row0 + wm + mi * 16 + quad * 4;
#pragma unroll
    for (int ni = 0; ni < 4; ++ni) {
      const int c = col0 + wn + ni * 16 + lane15;
#pragma unroll
      for (int r = 0; r < 4; ++r)
        C[(rbase + r) * Ndim + c] = acc[mi][ni][r];
    }
  }
}

// ------------------------------- launch -------------------------------------
extern "C" void kernel_launch(void* const* d_in, const int* in_sizes, int n_in,
                              void* d_out, int out_size, void* d_ws, size_t ws_size,
                              hipStream_t stream) {
  const float* x   = (const float*)d_in[0];
  const float* Wp  = (const float*)d_in[1];
  const float* Wc  = (const float*)d_in[2];
  const float* phi = (const float*)d_in[3];
  float* out = (float*)d_out;

  // ws: Qbf @0 (64 MB), Wpbf @67108864 (2 MB), Wcbf @69206016 (2 MB)
  char* ws = (char*)d_ws;
  unsigned short* Qbf  = (unsigned short*)(ws);
  unsigned short* Wpbf = (unsigned short*)(ws + (size_t)67108864);
  unsigned short* Wcbf = (unsigned short*)(ws + (size_t)69206016);

  cast_w<<<2048, 256, 0, stream>>>(Wp, Wc, Wpbf, Wcbf);
  gemm1_fused<<<2048, 256, 0, stream>>>(x, Wpbf, phi, Qbf);
  gemm2_bt<<<2048, 256, 0, stream>>>(Qbf, Wcbf, out);

  (void)in_sizes; (void)n_in; (void)out_size; (void)ws_size;
}